// Round 11
// baseline (389.418 us; speedup 1.0000x reference)
//
#include <hip/hip_runtime.h>

// RNN: B=4096, T=512, I=15, H=64, O=1
// R10b: R10 with the OOB x-read fixed (GPU fault in R10).
//  - g=1 lanes now load floats 7..14 of each row (in-row, never OOB) instead
//    of 8..15 (float 15 = next row; OOB by 4B at the very last row -> fault).
//    packx realigns pairs with per-element selects (cndmask, no scratch).
//  - Everything else identical to R10:
//    * symmetric 4-wave j-split, wave w owns tile jt=w (3 MFMA + 4 tanh/step)
//    * x straight from global into 4-deep register ring (no LDS x-ring)
//    * accx: x-MFMA for step t+1 precomputed during step t (bias C-init)
//    * pairwise-shared rcp tanh: 4 exp2 + 2 rcp per step
//    * h exchange hx[2][4][64] dbuf, 1 ds_write_b64 + 4 ds_read_b64/step,
//      one lgkmcnt(0)+s_barrier per step.

#define T_STEPS 512
#define I_DIM 15
#define BPW 16

typedef _Float16 half8 __attribute__((ext_vector_type(8)));
typedef __attribute__((ext_vector_type(4))) float float4v;
typedef __attribute__((ext_vector_type(4))) unsigned int uint4v;

union H8U { half8 h; uint4v u; };

// pack two f32 -> f16 pair, RNE
__device__ __forceinline__ unsigned pkh(float a, float b) {
    union { _Float16 h; unsigned short u; } A, B;
    A.h = (_Float16)a;
    B.h = (_Float16)b;
    return (unsigned)A.u | ((unsigned)B.u << 16);
}
// pack two f32 -> f16 pair, RTZ, single v_cvt_pkrtz_f16_f32
__device__ __forceinline__ unsigned pkz(float a, float b) {
    auto r = __builtin_amdgcn_cvt_pkrtz(a, b);
    unsigned u;
    __builtin_memcpy(&u, &r, 4);
    return u;
}
// build x B-frag from 8 loaded floats.
// g=0: rows k=64..71 -> x[0..7]  = v[0..7]
// g=1: rows k=72..79 -> x[8..14],0 ; v[] holds floats 7..14 -> use v[1..7],0
// per-element ternaries = v_cndmask on registers (no runtime indexing).
__device__ __forceinline__ uint4v packx(const float* v, int g) {
    float a0 = g ? v[1] : v[0];
    float a1 = g ? v[2] : v[1];
    float a2 = g ? v[3] : v[2];
    float a3 = g ? v[4] : v[3];
    float a4 = g ? v[5] : v[4];
    float a5 = g ? v[6] : v[5];
    float a6 = g ? v[7] : v[6];
    float a7 = g ? 0.f  : v[7];
    return (uint4v){ pkh(a0, a1), pkh(a2, a3), pkh(a4, a5), pkh(a6, a7) };
}

__global__ __launch_bounds__(256, 1) void rnn_fused(
    const float* __restrict__ x,     // [4096][512][15]
    const float* __restrict__ W_ih,  // [64][15]
    const float* __restrict__ W_hh,  // [64][64]
    const float* __restrict__ b_ih,  // [64]
    const float* __restrict__ b_hh,  // [64]
    const float* __restrict__ fc_w,  // [1][64]
    const float* __restrict__ fc_b,  // [1]
    float* __restrict__ out)         // [4096]
{
    __shared__ uint2 hx[2][4][64];   // 4 KB h exchange (dbuf by t&1)
    __shared__ float psum[4][16];    // head partials

    const int tid  = threadIdx.x;
    const int wave = tid >> 6;
    const int lane = tid & 63;
    const int q = lane >> 4;
    const int n = lane & 15;
    const int g = q & 1;                 // k-subgroup within x-chunk
    const int b0 = blockIdx.x * BPW;
    const int jt = wave;                 // this wave's j-tile
    const float K = 2.8853900817779268f; // 2/ln2 folded into W and bias

    // ---- own-tile A-frags (pi-permuted, K-scaled, fp16), bias, head w ----
    half8 whf[3];
    float4v cbv;
    float fcwv[4];
    const int jcol = 32*(jt>>1) + 8*(n>>2) + 4*(jt&1) + (n&3);   // pi(jt, n)
    #pragma unroll
    for (int c = 0; c < 3; c++) {
        #pragma unroll
        for (int e = 0; e < 8; e++) {
            const int k = c*32 + q*8 + e;
            float w = 0.f;
            if (k < 64)      w = W_hh[jcol*64 + k] * K;
            else if (k < 79) w = W_ih[jcol*15 + (k - 64)] * K;
            whf[c][e] = (_Float16)w;                             // RNE
        }
    }
    #pragma unroll
    for (int r = 0; r < 4; r++) {
        const int jr = 32*(jt>>1) + 8*q + 4*(jt&1) + r;          // pi(jt, 4q+r)
        cbv[r]  = K * (b_ih[jr] + b_hh[jr]);
        fcwv[r] = fc_w[jr];
    }

    // ---- per-lane x stream: batch n, float offset g*7 within each row ----
    // (g=0 reads floats 0..7, g=1 reads floats 7..14: always within the row)
    const float* xl = x + (size_t)(b0 + n) * (T_STEPS * I_DIM) + g * 7;

    // 4-deep register ring of raw rows (32 VGPRs)
    float xs[4][8];
    #pragma unroll
    for (int s = 0; s < 4; ++s)
        __builtin_memcpy(xs[s], xl + (size_t)s * I_DIM, 32);

    hx[1][wave][lane] = uint2{0u, 0u};   // h(-1) = 0 (read at t=0)

    // precompute x-MFMA for t=0
    H8U xf0; xf0.u = packx(xs[0], g);
    float4v accx = __builtin_amdgcn_mfma_f32_16x16x32_f16(whf[2], xf0.h, cbv, 0, 0, 0);

    asm volatile("s_waitcnt lgkmcnt(0)\n\ts_barrier" ::: "memory");

    float4v acc;
    float hfin[4];

    #pragma unroll 1
    for (int it = 0; it < T_STEPS / 4; ++it) {
        #pragma unroll
        for (int u = 0; u < 4; ++u) {
            const int t = it * 4 + u;
            // h(t-1) exchange reads (parity: (t+1)&1 == (u+1)&1)
            const int pr = (u + 1) & 1;
            const uint2 h0a = hx[pr][0][lane];
            const uint2 h0b = hx[pr][1][lane];
            const uint2 h1a = hx[pr][2][lane];
            const uint2 h1b = hx[pr][3][lane];

            acc = accx;   // x(t) contribution + bias, computed last step

            // x pipeline (covers the ds_read latency):
            // pack x(t+1) from slot (u+1)&3, precompute accx for t+1,
            // refill slot u with x(t+4).
            H8U xfn; xfn.u = packx(xs[(u + 1) & 3], g);
            accx = __builtin_amdgcn_mfma_f32_16x16x32_f16(whf[2], xfn.h, cbv, 0, 0, 0);
            int tl = t + 4; if (tl > T_STEPS - 1) tl = T_STEPS - 1;
            __builtin_memcpy(xs[u], xl + (size_t)tl * I_DIM, 32);

            // recurrent MFMAs (same per-tile order as R9 => same trajectory)
            H8U hh0; hh0.u = (uint4v){h0a.x, h0a.y, h0b.x, h0b.y};
            acc = __builtin_amdgcn_mfma_f32_16x16x32_f16(whf[0], hh0.h, acc, 0, 0, 0);
            H8U hh1; hh1.u = (uint4v){h1a.x, h1a.y, h1b.x, h1b.y};
            acc = __builtin_amdgcn_mfma_f32_16x16x32_f16(whf[1], hh1.h, acc, 0, 0, 0);

            // tanh epilogue, pairwise-shared rcp: 4 exp2 + 2 rcp
            {
                float E0 = __builtin_amdgcn_exp2f(acc[0]) + 1.f;
                float E1 = __builtin_amdgcn_exp2f(acc[1]) + 1.f;
                float R0 = __builtin_amdgcn_rcpf(E0 * E1);
                float m0 = -2.f * R0;
                hfin[0] = __builtin_fmaf(E1, m0, 1.f);
                hfin[1] = __builtin_fmaf(E0, m0, 1.f);
                float E2 = __builtin_amdgcn_exp2f(acc[2]) + 1.f;
                float E3 = __builtin_amdgcn_exp2f(acc[3]) + 1.f;
                float R2 = __builtin_amdgcn_rcpf(E2 * E3);
                float m2 = -2.f * R2;
                hfin[2] = __builtin_fmaf(E3, m2, 1.f);
                hfin[3] = __builtin_fmaf(E2, m2, 1.f);
            }
            uint2 hp; hp.x = pkz(hfin[0], hfin[1]); hp.y = pkz(hfin[2], hfin[3]);
            hx[u & 1][wave][lane] = hp;

            asm volatile("s_waitcnt lgkmcnt(0)\n\ts_barrier" ::: "memory");
        }
    }

    // ---- head: partial over own tile, reduce over q, then over waves ----
    float s = 0.f;
    #pragma unroll
    for (int r = 0; r < 4; r++) s = __builtin_fmaf(hfin[r], fcwv[r], s);
    s += __shfl_xor(s, 16, 64);
    s += __shfl_xor(s, 32, 64);
    if (lane < 16) psum[wave][n] = s;
    __syncthreads();
    if (tid < 16)
        out[b0 + tid] = psum[0][tid] + psum[1][tid] + psum[2][tid]
                      + psum[3][tid] + fc_b[0];
}

extern "C" void kernel_launch(void* const* d_in, const int* in_sizes, int n_in,
                              void* d_out, int out_size, void* d_ws, size_t ws_size,
                              hipStream_t stream) {
    const float* x    = (const float*)d_in[0];
    const float* W_ih = (const float*)d_in[1];
    const float* W_hh = (const float*)d_in[2];
    const float* b_ih = (const float*)d_in[3];
    const float* b_hh = (const float*)d_in[4];
    const float* fc_w = (const float*)d_in[5];
    const float* fc_b = (const float*)d_in[6];
    float* out = (float*)d_out;

    rnn_fused<<<4096 / BPW, 256, 0, stream>>>(x, W_ih, W_hh, b_ih, b_hh,
                                              fc_w, fc_b, out);
}

// Round 12
// 327.403 us; speedup vs baseline: 1.1894x; 1.1894x over previous
//
#include <hip/hip_runtime.h>

// RNN: B=4096, T=512, I=15, H=64, O=1
// R11: R10b with the scratch bug fixed.
//  - R10b's xs[4][8] + packx(const float*) took the array's address ->
//    compiler kept it in SCRATCH (VGPR_Count=52 proved it): every step paid
//    scratch store+load, 259us vs R9's 139us.
//  - Fix: four NAMED float8 ext-vector registers xs0..xs3, rotated by a
//    fully-unrolled 4-step schedule; packx takes the vector BY VALUE; loads
//    via memcpy into a non-escaping local (SROA -> 2x global_load_dwordx4).
//  - Numerics bit-identical to R10b (passed, absmax 0.00390625): same RNE
//    x-pack, same MFMA order, same pairwise-rcp tanh.
//  - Structure recap: symmetric 4-wave j-split (wave w owns tile jt=w:
//    3 recurrent MFMAs + accx precompute + 4 exp2 + 2 rcp per step),
//    h exchange hx[2][4][64] (1 ds_write_b64 + 4 ds_read_b64, lane-linear),
//    one lgkmcnt(0)+s_barrier per step.

#define T_STEPS 512
#define I_DIM 15
#define BPW 16

typedef _Float16 half8 __attribute__((ext_vector_type(8)));
typedef float float8v __attribute__((ext_vector_type(8)));
typedef __attribute__((ext_vector_type(4))) float float4v;
typedef __attribute__((ext_vector_type(4))) unsigned int uint4v;

union H8U { half8 h; uint4v u; };

// pack two f32 -> f16 pair, RNE
__device__ __forceinline__ unsigned pkh(float a, float b) {
    union { _Float16 h; unsigned short u; } A, B;
    A.h = (_Float16)a;
    B.h = (_Float16)b;
    return (unsigned)A.u | ((unsigned)B.u << 16);
}
// pack two f32 -> f16 pair, RTZ, single v_cvt_pkrtz_f16_f32
__device__ __forceinline__ unsigned pkz(float a, float b) {
    auto r = __builtin_amdgcn_cvt_pkrtz(a, b);
    unsigned u;
    __builtin_memcpy(&u, &r, 4);
    return u;
}
// load 8 floats into a register vector (non-escaping local -> SROA -> 2x dwordx4)
__device__ __forceinline__ float8v load8(const float* p) {
    float8v r;
    __builtin_memcpy(&r, p, 32);
    return r;
}
// build x B-frag from a row vector (BY VALUE -> stays in VGPRs).
// g=0: rows k=64..71 -> v[0..7] ; g=1: rows k=72..79 -> v[1..7],0
__device__ __forceinline__ uint4v packx(float8v v, int g) {
    float a0 = g ? v[1] : v[0];
    float a1 = g ? v[2] : v[1];
    float a2 = g ? v[3] : v[2];
    float a3 = g ? v[4] : v[3];
    float a4 = g ? v[5] : v[4];
    float a5 = g ? v[6] : v[5];
    float a6 = g ? v[7] : v[6];
    float a7 = g ? 0.f  : v[7];
    return (uint4v){ pkh(a0, a1), pkh(a2, a3), pkh(a4, a5), pkh(a6, a7) };
}

__global__ __launch_bounds__(256, 1) void rnn_fused(
    const float* __restrict__ x,     // [4096][512][15]
    const float* __restrict__ W_ih,  // [64][15]
    const float* __restrict__ W_hh,  // [64][64]
    const float* __restrict__ b_ih,  // [64]
    const float* __restrict__ b_hh,  // [64]
    const float* __restrict__ fc_w,  // [1][64]
    const float* __restrict__ fc_b,  // [1]
    float* __restrict__ out)         // [4096]
{
    __shared__ uint2 hx[2][4][64];   // 4 KB h exchange (dbuf by t&1)
    __shared__ float psum[4][16];    // head partials

    const int tid  = threadIdx.x;
    const int wave = tid >> 6;
    const int lane = tid & 63;
    const int q = lane >> 4;
    const int n = lane & 15;
    const int g = q & 1;                 // k-subgroup within x-chunk
    const int b0 = blockIdx.x * BPW;
    const int jt = wave;                 // this wave's j-tile
    const float K = 2.8853900817779268f; // 2/ln2 folded into W and bias

    // ---- own-tile A-frags (pi-permuted, K-scaled, fp16), bias, head w ----
    half8 whf[3];
    float4v cbv;
    float fcwv[4];
    const int jcol = 32*(jt>>1) + 8*(n>>2) + 4*(jt&1) + (n&3);   // pi(jt, n)
    #pragma unroll
    for (int c = 0; c < 3; c++) {
        #pragma unroll
        for (int e = 0; e < 8; e++) {
            const int k = c*32 + q*8 + e;
            float w = 0.f;
            if (k < 64)      w = W_hh[jcol*64 + k] * K;
            else if (k < 79) w = W_ih[jcol*15 + (k - 64)] * K;
            whf[c][e] = (_Float16)w;                             // RNE
        }
    }
    #pragma unroll
    for (int r = 0; r < 4; r++) {
        const int jr = 32*(jt>>1) + 8*q + 4*(jt&1) + r;          // pi(jt, 4q+r)
        cbv[r]  = K * (b_ih[jr] + b_hh[jr]);
        fcwv[r] = fc_w[jr];
    }

    // ---- per-lane x stream: batch n, float offset g*7 within each row ----
    // (g=0 reads floats 0..7, g=1 reads floats 7..14: always within the row)
    const float* xl = x + (size_t)(b0 + n) * (T_STEPS * I_DIM) + g * 7;

    // 4-deep register ring in NAMED vector registers
    float8v xs0 = load8(xl + 0 * I_DIM);
    float8v xs1 = load8(xl + 1 * I_DIM);
    float8v xs2 = load8(xl + 2 * I_DIM);
    float8v xs3 = load8(xl + 3 * I_DIM);

    hx[1][wave][lane] = uint2{0u, 0u};   // h(-1) = 0 (read at t=0)

    // precompute x-MFMA for t=0
    H8U xf0; xf0.u = packx(xs0, g);
    float4v accx = __builtin_amdgcn_mfma_f32_16x16x32_f16(whf[2], xf0.h, cbv, 0, 0, 0);

    asm volatile("s_waitcnt lgkmcnt(0)\n\ts_barrier" ::: "memory");

    float4v acc;
    float hfin[4];

    // One step: PKSLOT = slot holding x(t+1); RFSLOT = slot to refill x(t+4)
#define STEP_BODY(t, PKSLOT, RFSLOT) do {                                         \
        const int pr = ((t) + 1) & 1;                                             \
        const uint2 h0a = hx[pr][0][lane];                                        \
        const uint2 h0b = hx[pr][1][lane];                                        \
        const uint2 h1a = hx[pr][2][lane];                                        \
        const uint2 h1b = hx[pr][3][lane];                                        \
        acc = accx;                                                               \
        H8U xfn; xfn.u = packx(PKSLOT, g);                                        \
        accx = __builtin_amdgcn_mfma_f32_16x16x32_f16(whf[2], xfn.h, cbv, 0, 0, 0); \
        int tl = (t) + 4; if (tl > T_STEPS - 1) tl = T_STEPS - 1;                 \
        RFSLOT = load8(xl + (size_t)tl * I_DIM);                                  \
        H8U hh0; hh0.u = (uint4v){h0a.x, h0a.y, h0b.x, h0b.y};                    \
        acc = __builtin_amdgcn_mfma_f32_16x16x32_f16(whf[0], hh0.h, acc, 0, 0, 0);\
        H8U hh1; hh1.u = (uint4v){h1a.x, h1a.y, h1b.x, h1b.y};                    \
        acc = __builtin_amdgcn_mfma_f32_16x16x32_f16(whf[1], hh1.h, acc, 0, 0, 0);\
        {                                                                         \
            float E0 = __builtin_amdgcn_exp2f(acc[0]) + 1.f;                      \
            float E1 = __builtin_amdgcn_exp2f(acc[1]) + 1.f;                      \
            float R0 = __builtin_amdgcn_rcpf(E0 * E1);                            \
            float m0 = -2.f * R0;                                                 \
            hfin[0] = __builtin_fmaf(E1, m0, 1.f);                                \
            hfin[1] = __builtin_fmaf(E0, m0, 1.f);                                \
            float E2 = __builtin_amdgcn_exp2f(acc[2]) + 1.f;                      \
            float E3 = __builtin_amdgcn_exp2f(acc[3]) + 1.f;                      \
            float R2 = __builtin_amdgcn_rcpf(E2 * E3);                            \
            float m2 = -2.f * R2;                                                 \
            hfin[2] = __builtin_fmaf(E3, m2, 1.f);                                \
            hfin[3] = __builtin_fmaf(E2, m2, 1.f);                                \
        }                                                                         \
        uint2 hp; hp.x = pkz(hfin[0], hfin[1]); hp.y = pkz(hfin[2], hfin[3]);     \
        hx[(t) & 1][wave][lane] = hp;                                             \
        asm volatile("s_waitcnt lgkmcnt(0)\n\ts_barrier" ::: "memory");           \
    } while (0)

    #pragma unroll 1
    for (int it = 0; it < T_STEPS / 4; ++it) {
        const int t0 = it * 4;
        STEP_BODY(t0 + 0, xs1, xs0);   // pack x(t0+1), refill x(t0+4) -> slot 0
        STEP_BODY(t0 + 1, xs2, xs1);   // pack x(t0+2), refill x(t0+5) -> slot 1
        STEP_BODY(t0 + 2, xs3, xs2);   // pack x(t0+3), refill x(t0+6) -> slot 2
        STEP_BODY(t0 + 3, xs0, xs3);   // pack x(t0+4), refill x(t0+7) -> slot 3
    }
#undef STEP_BODY

    // ---- head: partial over own tile, reduce over q, then over waves ----
    float s = 0.f;
    #pragma unroll
    for (int r = 0; r < 4; r++) s = __builtin_fmaf(hfin[r], fcwv[r], s);
    s += __shfl_xor(s, 16, 64);
    s += __shfl_xor(s, 32, 64);
    if (lane < 16) psum[wave][n] = s;
    __syncthreads();
    if (tid < 16)
        out[b0 + tid] = psum[0][tid] + psum[1][tid] + psum[2][tid]
                      + psum[3][tid] + fc_b[0];
}

extern "C" void kernel_launch(void* const* d_in, const int* in_sizes, int n_in,
                              void* d_out, int out_size, void* d_ws, size_t ws_size,
                              hipStream_t stream) {
    const float* x    = (const float*)d_in[0];
    const float* W_ih = (const float*)d_in[1];
    const float* W_hh = (const float*)d_in[2];
    const float* b_ih = (const float*)d_in[3];
    const float* b_hh = (const float*)d_in[4];
    const float* fc_w = (const float*)d_in[5];
    const float* fc_b = (const float*)d_in[6];
    float* out = (float*)d_out;

    rnn_fused<<<4096 / BPW, 256, 0, stream>>>(x, W_ih, W_hh, b_ih, b_hh,
                                              fc_w, fc_b, out);
}